// Round 1
// baseline (1083.115 us; speedup 1.0000x reference)
//
#include <hip/hip_runtime.h>

constexpr int N  = 16384;
constexpr int D  = 64;
constexpr int H  = 256;
constexpr int SB = 16;          // samples per tile

// X[k][h] = W2[h][k]  (so forward z2 reads coalesced rows of X)
__global__ void transpose_w2(const float* __restrict__ W2, float* __restrict__ X) {
    int k = blockIdx.x;
    int h = threadIdx.x;
    X[k * H + h] = W2[h * H + k];
}

__global__ __launch_bounds__(256) void fused_lyap(
    const float* __restrict__ S,  const float* __restrict__ Sdot,
    const float* __restrict__ W1, const float* __restrict__ b1,
    const float* __restrict__ W2, const float* __restrict__ b2,
    const float* __restrict__ W3, const float* __restrict__ X,
    float* __restrict__ out)
{
    __shared__ float s_lds [SB][D];     // 4 KB
    __shared__ float sd_lds[SB][D];     // 4 KB
    __shared__ float yT[H][20];         // 20 KB, padded (80 B rows, 16B-aligned); y1 then g2
    __shared__ float red[4][SB][2];     // cross-wave reduction scratch

    const int h    = threadIdx.x;       // hidden unit
    const int tile = blockIdx.x;
    const int s0   = tile * SB;

    // ---- per-thread weight row of W1 in registers (16 x float4 = 64 VGPRs)
    float4 w1v[16];
    #pragma unroll
    for (int j = 0; j < 16; ++j)
        w1v[j] = reinterpret_cast<const float4*>(W1 + h * D)[j];
    const float b1h = b1[h];
    const float b2h = b2[h];
    const float w3h = W3[h];

    // ---- stage S / Sdot tile (1024 floats each = exactly 256 float4 loads)
    reinterpret_cast<float4*>(&s_lds [0][0])[h] = reinterpret_cast<const float4*>(S    + s0 * D)[h];
    reinterpret_cast<float4*>(&sd_lds[0][0])[h] = reinterpret_cast<const float4*>(Sdot + s0 * D)[h];
    __syncthreads();

    // ---- phase 1: z1[i] = W1[h]·s[i] + b1h ; u1[i] = W1[h]·sdot[i]
    float z1r[SB], u1r[SB];
    #pragma unroll
    for (int i = 0; i < SB; ++i) { z1r[i] = b1h; u1r[i] = 0.f; }
    #pragma unroll
    for (int j = 0; j < 16; ++j) {
        const float4 w = w1v[j];
        #pragma unroll
        for (int i = 0; i < SB; ++i) {
            const float4 sv = reinterpret_cast<const float4*>(&s_lds [i][0])[j];
            const float4 dv = reinterpret_cast<const float4*>(&sd_lds[i][0])[j];
            z1r[i] += w.x*sv.x + w.y*sv.y + w.z*sv.z + w.w*sv.w;
            u1r[i] += w.x*dv.x + w.y*dv.y + w.z*dv.z + w.w*dv.w;
        }
    }

    // y1 transposed into LDS: yT[k=h][i]
    #pragma unroll
    for (int i = 0; i < SB; ++i) yT[h][i] = z1r[i] * z1r[i];
    __syncthreads();

    // ---- phase 2: z2[i] = b2h + sum_k X[k][h] * y1[i][k]
    float z2r[SB];
    #pragma unroll
    for (int i = 0; i < SB; ++i) z2r[i] = b2h;
    #pragma unroll 4
    for (int k = 0; k < H; ++k) {
        const float xv = X[k * H + h];                       // coalesced 256B row
        const float4 y0 = *reinterpret_cast<const float4*>(&yT[k][0]);
        const float4 y1_ = *reinterpret_cast<const float4*>(&yT[k][4]);
        const float4 y2_ = *reinterpret_cast<const float4*>(&yT[k][8]);
        const float4 y3_ = *reinterpret_cast<const float4*>(&yT[k][12]);
        z2r[ 0] += xv * y0.x;  z2r[ 1] += xv * y0.y;  z2r[ 2] += xv * y0.z;  z2r[ 3] += xv * y0.w;
        z2r[ 4] += xv * y1_.x; z2r[ 5] += xv * y1_.y; z2r[ 6] += xv * y1_.z; z2r[ 7] += xv * y1_.w;
        z2r[ 8] += xv * y2_.x; z2r[ 9] += xv * y2_.y; z2r[10] += xv * y2_.z; z2r[11] += xv * y2_.w;
        z2r[12] += xv * y3_.x; z2r[13] += xv * y3_.y; z2r[14] += xv * y3_.z; z2r[15] += xv * y3_.w;
    }
    __syncthreads();   // all reads of y1 done before overwrite

    // g2 transposed into LDS: g2[i][k=h] = W3[h] * 2 * z2[i]
    #pragma unroll
    for (int i = 0; i < SB; ++i) yT[h][i] = w3h * 2.f * z2r[i];
    __syncthreads();

    // ---- phase 3 (backward): t[i] = sum_k W2[k][h] * g2[i][k]
    float tacc[SB];
    #pragma unroll
    for (int i = 0; i < SB; ++i) tacc[i] = 0.f;
    #pragma unroll 4
    for (int k = 0; k < H; ++k) {
        const float wv = W2[k * H + h];                      // coalesced 256B row
        const float4 g0 = *reinterpret_cast<const float4*>(&yT[k][0]);
        const float4 g1_ = *reinterpret_cast<const float4*>(&yT[k][4]);
        const float4 g2_ = *reinterpret_cast<const float4*>(&yT[k][8]);
        const float4 g3_ = *reinterpret_cast<const float4*>(&yT[k][12]);
        tacc[ 0] += wv * g0.x;  tacc[ 1] += wv * g0.y;  tacc[ 2] += wv * g0.z;  tacc[ 3] += wv * g0.w;
        tacc[ 4] += wv * g1_.x; tacc[ 5] += wv * g1_.y; tacc[ 6] += wv * g1_.z; tacc[ 7] += wv * g1_.w;
        tacc[ 8] += wv * g2_.x; tacc[ 9] += wv * g2_.y; tacc[10] += wv * g2_.z; tacc[11] += wv * g2_.w;
        tacc[12] += wv * g3_.x; tacc[13] += wv * g3_.y; tacc[14] += wv * g3_.z; tacc[15] += wv * g3_.w;
    }

    // ---- per-thread partials + wave reduction
    const int lane = h & 63;
    const int wid  = h >> 6;
    #pragma unroll
    for (int i = 0; i < SB; ++i) {
        float a = w3h * z2r[i] * z2r[i];                 // nn_out partial
        float b = (tacc[i] * 2.f * z1r[i]) * u1r[i];     // grad_nn·Sdot partial
        #pragma unroll
        for (int off = 32; off; off >>= 1) {
            a += __shfl_xor(a, off);
            b += __shfl_xor(b, off);
        }
        if (lane == 0) { red[wid][i][0] = a; red[wid][i][1] = b; }
    }
    __syncthreads();

    // ---- finalize: 16 threads, one sample each
    if (h < SB) {
        const int i = h;
        const float nn = red[0][i][0] + red[1][i][0] + red[2][i][0] + red[3][i][0];
        const float gd = red[0][i][1] + red[1][i][1] + red[2][i][1] + red[3][i][1];
        float c = 0.f, sd = 0.f;
        #pragma unroll
        for (int d = 0; d < D; ++d) {
            const float sv = s_lds[i][d];
            c  += sv * sv;
            sd += sv * sd_lds[i][d];
        }
        const int n = s0 + i;
        out[n]         = nn * c;                 // V
        out[N + n]     = 2.f * nn * sd + c * gd; // Vdot
        out[2 * N + n] = c;                      // circle
    }
}

extern "C" void kernel_launch(void* const* d_in, const int* in_sizes, int n_in,
                              void* d_out, int out_size, void* d_ws, size_t ws_size,
                              hipStream_t stream) {
    const float* S    = (const float*)d_in[0];
    const float* Sdot = (const float*)d_in[1];
    const float* W1   = (const float*)d_in[2];
    const float* b1   = (const float*)d_in[3];
    const float* W2   = (const float*)d_in[4];
    const float* b2   = (const float*)d_in[5];
    const float* W3   = (const float*)d_in[6];
    float* out = (float*)d_out;
    float* X   = (float*)d_ws;     // 256*256*4 = 256 KB for W2^T

    transpose_w2<<<H, H, 0, stream>>>(W2, X);
    fused_lyap<<<N / SB, 256, 0, stream>>>(S, Sdot, W1, b1, W2, b2, W3, X, out);
}

// Round 2
// 156.247 us; speedup vs baseline: 6.9321x; 6.9321x over previous
//
#include <hip/hip_runtime.h>

constexpr int N  = 16384;
constexpr int D  = 64;
constexpr int H  = 256;
constexpr int SB = 16;          // samples per tile

// X[k][h] = W2[h][k]  (so forward z2 reads coalesced rows of X)
__global__ void transpose_w2(const float* __restrict__ W2, float* __restrict__ X) {
    int k = blockIdx.x;
    int h = threadIdx.x;
    X[k * H + h] = W2[h * H + k];
}

__global__ __launch_bounds__(256, 4) void fused_lyap(
    const float* __restrict__ S,  const float* __restrict__ Sdot,
    const float* __restrict__ W1, const float* __restrict__ b1,
    const float* __restrict__ W2, const float* __restrict__ b2,
    const float* __restrict__ W3, const float* __restrict__ X,
    float* __restrict__ out)
{
    __shared__ float s_lds [SB][D];     // 4 KB
    __shared__ float sd_lds[SB][D];     // 4 KB
    __shared__ float yT[H][20];         // 20 KB, padded rows (80 B, 16B-aligned)
    __shared__ float red[4][SB][2];     // cross-wave reduction scratch
    __shared__ float csd[SB][2];        // per-sample circle, s.sdot

    const int h  = threadIdx.x;         // hidden unit
    const int s0 = blockIdx.x * SB;

    // ---- stage S / Sdot tile; fuse circle & s.sdot partial reduction.
    // thread h loads float4 #h -> belongs to sample h/16 (16 float4 per sample)
    {
        const float4 sv = reinterpret_cast<const float4*>(S    + s0 * D)[h];
        const float4 dv = reinterpret_cast<const float4*>(Sdot + s0 * D)[h];
        reinterpret_cast<float4*>(&s_lds [0][0])[h] = sv;
        reinterpret_cast<float4*>(&sd_lds[0][0])[h] = dv;
        float c  = sv.x*sv.x + sv.y*sv.y + sv.z*sv.z + sv.w*sv.w;
        float sd = sv.x*dv.x + sv.y*dv.y + sv.z*dv.z + sv.w*dv.w;
        #pragma unroll
        for (int off = 1; off < 16; off <<= 1) {   // 16 threads per sample, same wave
            c  += __shfl_xor(c,  off);
            sd += __shfl_xor(sd, off);
        }
        if ((h & 15) == 0) { csd[h >> 4][0] = c; csd[h >> 4][1] = sd; }
    }
    const float b1h = b1[h];
    const float b2h = b2[h];
    const float w3h = W3[h];
    __syncthreads();

    // ---- phase 1: z1[i] = W1[h].s[i] + b1h ; u1[i] = W1[h].sdot[i]
    // W1 row streamed from global (L2-resident) -- do NOT hold 64 VGPRs of it.
    float z1r[SB], u1r[SB];
    #pragma unroll
    for (int i = 0; i < SB; ++i) { z1r[i] = b1h; u1r[i] = 0.f; }
    {
        const float4* w1p = reinterpret_cast<const float4*>(W1 + h * D);
        #pragma unroll 4
        for (int j = 0; j < 16; ++j) {
            const float4 w = w1p[j];
            #pragma unroll
            for (int i = 0; i < SB; ++i) {
                const float4 sv = reinterpret_cast<const float4*>(&s_lds [i][0])[j];
                const float4 dv = reinterpret_cast<const float4*>(&sd_lds[i][0])[j];
                z1r[i] += w.x*sv.x + w.y*sv.y + w.z*sv.z + w.w*sv.w;
                u1r[i] += w.x*dv.x + w.y*dv.y + w.z*dv.z + w.w*dv.w;
            }
        }
    }

    // collapse z1,u1 -> p (frees 32 regs); publish y1 = z1^2 transposed
    float p[SB];
    #pragma unroll
    for (int i = 0; i < SB; ++i) p[i] = 2.f * z1r[i] * u1r[i];
    #pragma unroll
    for (int i = 0; i < SB; ++i) yT[h][i] = z1r[i] * z1r[i];
    __syncthreads();

    // ---- phase 2: z2[i] = b2h + sum_k X[k][h] * y1[i][k]   (yT reads broadcast)
    float z2r[SB];
    #pragma unroll
    for (int i = 0; i < SB; ++i) z2r[i] = b2h;
    {
        const float* Xc = X + h;
        #pragma unroll 4
        for (int k = 0; k < H; ++k) {
            const float xv = Xc[(size_t)k * H];              // coalesced 1KB/wave row
            const float4 y0  = *reinterpret_cast<const float4*>(&yT[k][0]);
            const float4 y1_ = *reinterpret_cast<const float4*>(&yT[k][4]);
            const float4 y2_ = *reinterpret_cast<const float4*>(&yT[k][8]);
            const float4 y3_ = *reinterpret_cast<const float4*>(&yT[k][12]);
            z2r[ 0] += xv * y0.x;  z2r[ 1] += xv * y0.y;  z2r[ 2] += xv * y0.z;  z2r[ 3] += xv * y0.w;
            z2r[ 4] += xv * y1_.x; z2r[ 5] += xv * y1_.y; z2r[ 6] += xv * y1_.z; z2r[ 7] += xv * y1_.w;
            z2r[ 8] += xv * y2_.x; z2r[ 9] += xv * y2_.y; z2r[10] += xv * y2_.z; z2r[11] += xv * y2_.w;
            z2r[12] += xv * y3_.x; z2r[13] += xv * y3_.y; z2r[14] += xv * y3_.z; z2r[15] += xv * y3_.w;
        }
    }
    __syncthreads();   // all reads of y1 done before overwrite

    // collapse z2 -> avec (nn_out partials); publish g2 = 2*W3[h]*z2 transposed
    float avec[SB];
    #pragma unroll
    for (int i = 0; i < SB; ++i) avec[i] = w3h * z2r[i] * z2r[i];
    #pragma unroll
    for (int i = 0; i < SB; ++i) yT[h][i] = (w3h * 2.f) * z2r[i];
    __syncthreads();

    // ---- phase 3 (backward): t[i] = sum_k W2[k][h] * g2[i][k]
    float tacc[SB];
    #pragma unroll
    for (int i = 0; i < SB; ++i) tacc[i] = 0.f;
    {
        const float* Wc = W2 + h;
        #pragma unroll 4
        for (int k = 0; k < H; ++k) {
            const float wv = Wc[(size_t)k * H];              // coalesced 1KB/wave row
            const float4 g0  = *reinterpret_cast<const float4*>(&yT[k][0]);
            const float4 g1_ = *reinterpret_cast<const float4*>(&yT[k][4]);
            const float4 g2_ = *reinterpret_cast<const float4*>(&yT[k][8]);
            const float4 g3_ = *reinterpret_cast<const float4*>(&yT[k][12]);
            tacc[ 0] += wv * g0.x;  tacc[ 1] += wv * g0.y;  tacc[ 2] += wv * g0.z;  tacc[ 3] += wv * g0.w;
            tacc[ 4] += wv * g1_.x; tacc[ 5] += wv * g1_.y; tacc[ 6] += wv * g1_.z; tacc[ 7] += wv * g1_.w;
            tacc[ 8] += wv * g2_.x; tacc[ 9] += wv * g2_.y; tacc[10] += wv * g2_.z; tacc[11] += wv * g2_.w;
            tacc[12] += wv * g3_.x; tacc[13] += wv * g3_.y; tacc[14] += wv * g3_.z; tacc[15] += wv * g3_.w;
        }
    }

    // ---- per-thread partials + wave reduction
    const int lane = h & 63;
    const int wid  = h >> 6;
    #pragma unroll
    for (int i = 0; i < SB; ++i) {
        float a = avec[i];           // nn_out partial
        float b = tacc[i] * p[i];    // grad_nn . Sdot partial
        #pragma unroll
        for (int off = 32; off; off >>= 1) {
            a += __shfl_xor(a, off);
            b += __shfl_xor(b, off);
        }
        if (lane == 0) { red[wid][i][0] = a; red[wid][i][1] = b; }
    }
    __syncthreads();

    // ---- finalize: 16 threads, one sample each
    if (h < SB) {
        const int i = h;
        const float nn = red[0][i][0] + red[1][i][0] + red[2][i][0] + red[3][i][0];
        const float gd = red[0][i][1] + red[1][i][1] + red[2][i][1] + red[3][i][1];
        const float c  = csd[i][0];
        const float sd = csd[i][1];
        const int n = s0 + i;
        out[n]         = nn * c;                 // V
        out[N + n]     = 2.f * nn * sd + c * gd; // Vdot
        out[2 * N + n] = c;                      // circle
    }
}

extern "C" void kernel_launch(void* const* d_in, const int* in_sizes, int n_in,
                              void* d_out, int out_size, void* d_ws, size_t ws_size,
                              hipStream_t stream) {
    const float* S    = (const float*)d_in[0];
    const float* Sdot = (const float*)d_in[1];
    const float* W1   = (const float*)d_in[2];
    const float* b1   = (const float*)d_in[3];
    const float* W2   = (const float*)d_in[4];
    const float* b2   = (const float*)d_in[5];
    const float* W3   = (const float*)d_in[6];
    float* out = (float*)d_out;
    float* X   = (float*)d_ws;     // 256*256*4 = 256 KB for W2^T

    transpose_w2<<<H, H, 0, stream>>>(W2, X);
    fused_lyap<<<N / SB, 256, 0, stream>>>(S, Sdot, W1, b1, W2, b2, W3, X, out);
}

// Round 3
// 38.366 us; speedup vs baseline: 28.2312x; 4.0726x over previous
//
#include <hip/hip_runtime.h>

typedef __attribute__((ext_vector_type(8))) short bf16x8;
typedef __attribute__((ext_vector_type(4))) float f32x4;

constexpr int N  = 16384;
constexpr int D  = 64;
constexpr int H  = 256;
constexpr int SB = 16;          // samples per tile

__device__ __forceinline__ ushort f2bf(float x) {
    uint u = __float_as_uint(x);
    u += 0x7fffu + ((u >> 16) & 1u);
    return (ushort)(u >> 16);
}
__device__ __forceinline__ float bf2f(ushort h) {
    return __uint_as_float(((uint)h) << 16);
}
// write/read swizzle on the i (sample) dim of the y planes: breaks the
// 8-way bank alias of the b16 transpose writes; bijective (low 2 bits kept).
__device__ __forceinline__ int phys_i(int i) { return i ^ ((i >> 2) & 3); }

// ---------------------------------------------------------------------------
// d_ws layout (ushort units):
//   B1h @ 0       (16384)   B1l @ 16384      rows c=h1, k=d     (= W1 rows)
//   B2h @ 32768   (65536)   B2l @ 98304      rows c=h2, k=h1    (= W2 rows)
//   B3h @ 163840  (65536)   B3l @ 229376     rows c=h1, k=h2    (= W2^T rows)
// frag layout per plane: flat = ((kc*4 + g)*C + c)*8 + j, k = kc*32 + g*8 + j
// total 294912 ushorts = 576 KB
// ---------------------------------------------------------------------------
__global__ void prep_weights(const float* __restrict__ W1, const float* __restrict__ W2,
                             ushort* __restrict__ ws) {
    const int idx = blockIdx.x * 256 + threadIdx.x;   // 0..65535
    {
        const int h2 = idx >> 8, h1 = idx & 255;
        const float x = W2[idx];                      // W2[h2][h1]
        const ushort xh = f2bf(x);
        const ushort xl = f2bf(x - bf2f(xh));
        const int d2 = (((h1 >> 5) * 4 + ((h1 >> 3) & 3)) * 256 + h2) * 8 + (h1 & 7);
        ws[32768 + d2] = xh;  ws[98304 + d2] = xl;
        const int d3 = (((h2 >> 5) * 4 + ((h2 >> 3) & 3)) * 256 + h1) * 8 + (h2 & 7);
        ws[163840 + d3] = xh; ws[229376 + d3] = xl;
    }
    if (idx < H * D) {
        const int h1 = idx >> 6, d = idx & 63;
        const float x = W1[idx];                      // W1[h1][d]
        const ushort xh = f2bf(x);
        const ushort xl = f2bf(x - bf2f(xh));
        const int d1 = (((d >> 5) * 4 + ((d >> 3) & 3)) * 256 + h1) * 8 + (d & 7);
        ws[d1] = xh; ws[16384 + d1] = xl;
    }
}

__global__ __launch_bounds__(256, 4) void fused_mfma(
    const float* __restrict__ S,  const float* __restrict__ Sdot,
    const float* __restrict__ b1, const float* __restrict__ b2,
    const float* __restrict__ W3, const ushort* __restrict__ ws,
    float* __restrict__ out)
{
    __shared__ float  s_lds [SB][68];   // +4 pad: frag reads 2-way (free)
    __shared__ float  sd_lds[SB][68];
    __shared__ ushort yH[4096];         // 8 KB: y1 / g2 hi plane, frag-ordered
    __shared__ ushort yL[4096];         // 8 KB: lo plane
    __shared__ float  red[2][4][16];    // [nn|gd][wave][sample]
    __shared__ float  csd[SB][2];       // per-sample circle, s.sdot

    const int t   = threadIdx.x;
    const int l   = t & 63;
    const int wid = t >> 6;
    const int lg  = l >> 4;             // lane group 0..3
    const int lc  = l & 15;             // lane row/col within tile
    const int s0  = blockIdx.x * SB;

    // ---- stage S/Sdot tile (f32), fused circle & s.sdot reduction
    {
        const float4 sv = reinterpret_cast<const float4*>(S    + s0 * D)[t];
        const float4 dv = reinterpret_cast<const float4*>(Sdot + s0 * D)[t];
        const int i = t >> 4, j = (t & 15) * 4;
        *reinterpret_cast<float4*>(&s_lds [i][j]) = sv;
        *reinterpret_cast<float4*>(&sd_lds[i][j]) = dv;
        float c  = sv.x*sv.x + sv.y*sv.y + sv.z*sv.z + sv.w*sv.w;
        float sd = sv.x*dv.x + sv.y*dv.y + sv.z*dv.z + sv.w*dv.w;
        #pragma unroll
        for (int off = 1; off < 16; off <<= 1) { c += __shfl_xor(c, off); sd += __shfl_xor(sd, off); }
        if ((t & 15) == 0) { csd[i][0] = c; csd[i][1] = sd; }
    }
    __syncthreads();

    // ---- phase 1: z1 = S@W1^T + b1, u1 = Sdot@W1^T   (MFMA, split-bf16)
    // A-frags from LDS: lane holds row i=lc, k = kc*32 + lg*8 + j
    bf16x8 sh[2], sl[2], dh2[2], dl2[2];
    #pragma unroll
    for (int kc = 0; kc < 2; ++kc) {
        const float* sp = &s_lds [lc][kc * 32 + lg * 8];
        const float* dp = &sd_lds[lc][kc * 32 + lg * 8];
        const float4 a0 = *reinterpret_cast<const float4*>(sp);
        const float4 a1 = *reinterpret_cast<const float4*>(sp + 4);
        const float4 c0 = *reinterpret_cast<const float4*>(dp);
        const float4 c1 = *reinterpret_cast<const float4*>(dp + 4);
        const float va[8] = {a0.x,a0.y,a0.z,a0.w,a1.x,a1.y,a1.z,a1.w};
        const float vc[8] = {c0.x,c0.y,c0.z,c0.w,c1.x,c1.y,c1.z,c1.w};
        #pragma unroll
        for (int j = 0; j < 8; ++j) {
            const ushort hv = f2bf(va[j]);
            sh[kc][j] = (short)hv;
            sl[kc][j] = (short)f2bf(va[j] - bf2f(hv));
            const ushort gv = f2bf(vc[j]);
            dh2[kc][j] = (short)gv;
            dl2[kc][j] = (short)f2bf(vc[j] - bf2f(gv));
        }
    }

    f32x4 z1acc[4], u1acc[4];
    #pragma unroll
    for (int q = 0; q < 4; ++q) { z1acc[q] = (f32x4){0,0,0,0}; u1acc[q] = (f32x4){0,0,0,0}; }
    {
        const ushort* B1h = ws;
        const ushort* B1l = ws + 16384;
        #pragma unroll
        for (int kc = 0; kc < 2; ++kc) {
            #pragma unroll
            for (int tt = 0; tt < 4; ++tt) {
                const int off = ((kc * 4 + lg) * 256 + (wid * 4 + tt) * 16 + lc) * 8;
                const bf16x8 bh = *reinterpret_cast<const bf16x8*>(B1h + off);
                const bf16x8 bl = *reinterpret_cast<const bf16x8*>(B1l + off);
                z1acc[tt] = __builtin_amdgcn_mfma_f32_16x16x32_bf16(sh[kc],  bh, z1acc[tt], 0,0,0);
                z1acc[tt] = __builtin_amdgcn_mfma_f32_16x16x32_bf16(sl[kc],  bh, z1acc[tt], 0,0,0);
                z1acc[tt] = __builtin_amdgcn_mfma_f32_16x16x32_bf16(sh[kc],  bl, z1acc[tt], 0,0,0);
                u1acc[tt] = __builtin_amdgcn_mfma_f32_16x16x32_bf16(dh2[kc], bh, u1acc[tt], 0,0,0);
                u1acc[tt] = __builtin_amdgcn_mfma_f32_16x16x32_bf16(dl2[kc], bh, u1acc[tt], 0,0,0);
                u1acc[tt] = __builtin_amdgcn_mfma_f32_16x16x32_bf16(dh2[kc], bl, u1acc[tt], 0,0,0);
            }
        }
    }

    // D layout: row(sample) = lg*4 + r, col(h) = tile*16 + lc
    // y1 = (z1+b1)^2 -> split bf16 -> y planes (transpose via LDS, swizzled i)
    f32x4 p[4];
    #pragma unroll
    for (int tt = 0; tt < 4; ++tt) {
        const int h = (wid * 4 + tt) * 16 + lc;
        const float bb = b1[h];
        const int ybase = (h >> 5) * 512 + ((h >> 3) & 3) * 128 + (h & 7);
        #pragma unroll
        for (int r = 0; r < 4; ++r) {
            const float z = z1acc[tt][r] + bb;
            p[tt][r] = 2.f * z * u1acc[tt][r];
            const float y  = z * z;
            const ushort yh_ = f2bf(y);
            const ushort yl_ = f2bf(y - bf2f(yh_));
            const int ii = phys_i(lg * 4 + r);
            yH[ybase + ii * 8] = yh_;
            yL[ybase + ii * 8] = yl_;
        }
    }
    __syncthreads();

    // ---- phase 2: z2 = y1 @ W2^T + b2  (A rows = samples from y planes)
    f32x4 z2acc[4];
    #pragma unroll
    for (int q = 0; q < 4; ++q) z2acc[q] = (f32x4){0,0,0,0};
    const int aoff = (lg * 16 + phys_i(lc)) * 8;
    {
        const ushort* B2h = ws + 32768;
        const ushort* B2l = ws + 98304;
        #pragma unroll 2
        for (int kc = 0; kc < 8; ++kc) {
            const bf16x8 ah = *reinterpret_cast<const bf16x8*>(&yH[kc * 512 + aoff]);
            const bf16x8 al = *reinterpret_cast<const bf16x8*>(&yL[kc * 512 + aoff]);
            #pragma unroll
            for (int tt = 0; tt < 4; ++tt) {
                const int off = ((kc * 4 + lg) * 256 + (wid * 4 + tt) * 16 + lc) * 8;
                const bf16x8 bh = *reinterpret_cast<const bf16x8*>(B2h + off);
                const bf16x8 bl = *reinterpret_cast<const bf16x8*>(B2l + off);
                z2acc[tt] = __builtin_amdgcn_mfma_f32_16x16x32_bf16(ah, bh, z2acc[tt], 0,0,0);
                z2acc[tt] = __builtin_amdgcn_mfma_f32_16x16x32_bf16(al, bh, z2acc[tt], 0,0,0);
                z2acc[tt] = __builtin_amdgcn_mfma_f32_16x16x32_bf16(ah, bl, z2acc[tt], 0,0,0);
            }
        }
    }
    __syncthreads();   // every wave done READING y1 before g2 overwrite

    // nn partials + publish g2 = 2*W3*z2
    float nnp[4] = {0.f, 0.f, 0.f, 0.f};
    #pragma unroll
    for (int tt = 0; tt < 4; ++tt) {
        const int h = (wid * 4 + tt) * 16 + lc;
        const float bb = b2[h];
        const float w3 = W3[h];
        const int ybase = (h >> 5) * 512 + ((h >> 3) & 3) * 128 + (h & 7);
        #pragma unroll
        for (int r = 0; r < 4; ++r) {
            const float z = z2acc[tt][r] + bb;
            nnp[r] += w3 * z * z;
            const float g = 2.f * w3 * z;
            const ushort gh = f2bf(g);
            const ushort gl = f2bf(g - bf2f(gh));
            const int ii = phys_i(lg * 4 + r);
            yH[ybase + ii * 8] = gh;
            yL[ybase + ii * 8] = gl;
        }
    }
    #pragma unroll
    for (int r = 0; r < 4; ++r) {
        #pragma unroll
        for (int off = 1; off < 16; off <<= 1) nnp[r] += __shfl_xor(nnp[r], off);
    }
    if (lc == 0)
        *reinterpret_cast<float4*>(&red[0][wid][lg * 4]) = make_float4(nnp[0], nnp[1], nnp[2], nnp[3]);
    __syncthreads();   // g2 planes visible

    // ---- phase 3: t = g2 @ W2  (B rows = W2^T rows)
    f32x4 tacc[4];
    #pragma unroll
    for (int q = 0; q < 4; ++q) tacc[q] = (f32x4){0,0,0,0};
    {
        const ushort* B3h = ws + 163840;
        const ushort* B3l = ws + 229376;
        #pragma unroll 2
        for (int kc = 0; kc < 8; ++kc) {
            const bf16x8 ah = *reinterpret_cast<const bf16x8*>(&yH[kc * 512 + aoff]);
            const bf16x8 al = *reinterpret_cast<const bf16x8*>(&yL[kc * 512 + aoff]);
            #pragma unroll
            for (int tt = 0; tt < 4; ++tt) {
                const int off = ((kc * 4 + lg) * 256 + (wid * 4 + tt) * 16 + lc) * 8;
                const bf16x8 bh = *reinterpret_cast<const bf16x8*>(B3h + off);
                const bf16x8 bl = *reinterpret_cast<const bf16x8*>(B3l + off);
                tacc[tt] = __builtin_amdgcn_mfma_f32_16x16x32_bf16(ah, bh, tacc[tt], 0,0,0);
                tacc[tt] = __builtin_amdgcn_mfma_f32_16x16x32_bf16(al, bh, tacc[tt], 0,0,0);
                tacc[tt] = __builtin_amdgcn_mfma_f32_16x16x32_bf16(ah, bl, tacc[tt], 0,0,0);
            }
        }
    }
    float gdp[4] = {0.f, 0.f, 0.f, 0.f};
    #pragma unroll
    for (int tt = 0; tt < 4; ++tt) {
        #pragma unroll
        for (int r = 0; r < 4; ++r) gdp[r] += tacc[tt][r] * p[tt][r];
    }
    #pragma unroll
    for (int r = 0; r < 4; ++r) {
        #pragma unroll
        for (int off = 1; off < 16; off <<= 1) gdp[r] += __shfl_xor(gdp[r], off);
    }
    if (lc == 0)
        *reinterpret_cast<float4*>(&red[1][wid][lg * 4]) = make_float4(gdp[0], gdp[1], gdp[2], gdp[3]);
    __syncthreads();

    // ---- finalize
    if (t < SB) {
        const int i = t;
        const float nn = red[0][0][i] + red[0][1][i] + red[0][2][i] + red[0][3][i];
        const float gd = red[1][0][i] + red[1][1][i] + red[1][2][i] + red[1][3][i];
        const float c  = csd[i][0];
        const float sd = csd[i][1];
        const int n = s0 + i;
        out[n]         = nn * c;
        out[N + n]     = 2.f * nn * sd + c * gd;
        out[2 * N + n] = c;
    }
}

// ======================= fallback (round-2 kernel) =========================
__global__ void transpose_w2(const float* __restrict__ W2, float* __restrict__ X) {
    int k = blockIdx.x;
    int h = threadIdx.x;
    X[k * H + h] = W2[h * H + k];
}

__global__ __launch_bounds__(256, 4) void fused_lyap(
    const float* __restrict__ S,  const float* __restrict__ Sdot,
    const float* __restrict__ W1, const float* __restrict__ b1,
    const float* __restrict__ W2, const float* __restrict__ b2,
    const float* __restrict__ W3, const float* __restrict__ X,
    float* __restrict__ out)
{
    __shared__ float s_lds [SB][D];
    __shared__ float sd_lds[SB][D];
    __shared__ float yT[H][20];
    __shared__ float red[4][SB][2];
    __shared__ float csd[SB][2];

    const int h  = threadIdx.x;
    const int s0 = blockIdx.x * SB;
    {
        const float4 sv = reinterpret_cast<const float4*>(S    + s0 * D)[h];
        const float4 dv = reinterpret_cast<const float4*>(Sdot + s0 * D)[h];
        reinterpret_cast<float4*>(&s_lds [0][0])[h] = sv;
        reinterpret_cast<float4*>(&sd_lds[0][0])[h] = dv;
        float c  = sv.x*sv.x + sv.y*sv.y + sv.z*sv.z + sv.w*sv.w;
        float sd = sv.x*dv.x + sv.y*dv.y + sv.z*dv.z + sv.w*dv.w;
        #pragma unroll
        for (int off = 1; off < 16; off <<= 1) { c += __shfl_xor(c, off); sd += __shfl_xor(sd, off); }
        if ((h & 15) == 0) { csd[h >> 4][0] = c; csd[h >> 4][1] = sd; }
    }
    const float b1h = b1[h];
    const float b2h = b2[h];
    const float w3h = W3[h];
    __syncthreads();

    float z1r[SB], u1r[SB];
    #pragma unroll
    for (int i = 0; i < SB; ++i) { z1r[i] = b1h; u1r[i] = 0.f; }
    {
        const float4* w1p = reinterpret_cast<const float4*>(W1 + h * D);
        #pragma unroll 4
        for (int j = 0; j < 16; ++j) {
            const float4 w = w1p[j];
            #pragma unroll
            for (int i = 0; i < SB; ++i) {
                const float4 sv = reinterpret_cast<const float4*>(&s_lds [i][0])[j];
                const float4 dv = reinterpret_cast<const float4*>(&sd_lds[i][0])[j];
                z1r[i] += w.x*sv.x + w.y*sv.y + w.z*sv.z + w.w*sv.w;
                u1r[i] += w.x*dv.x + w.y*dv.y + w.z*dv.z + w.w*dv.w;
            }
        }
    }
    float p[SB];
    #pragma unroll
    for (int i = 0; i < SB; ++i) p[i] = 2.f * z1r[i] * u1r[i];
    #pragma unroll
    for (int i = 0; i < SB; ++i) yT[h][i] = z1r[i] * z1r[i];
    __syncthreads();

    float z2r[SB];
    #pragma unroll
    for (int i = 0; i < SB; ++i) z2r[i] = b2h;
    {
        const float* Xc = X + h;
        #pragma unroll 4
        for (int k = 0; k < H; ++k) {
            const float xv = Xc[(size_t)k * H];
            const float4 y0  = *reinterpret_cast<const float4*>(&yT[k][0]);
            const float4 y1_ = *reinterpret_cast<const float4*>(&yT[k][4]);
            const float4 y2_ = *reinterpret_cast<const float4*>(&yT[k][8]);
            const float4 y3_ = *reinterpret_cast<const float4*>(&yT[k][12]);
            z2r[ 0] += xv * y0.x;  z2r[ 1] += xv * y0.y;  z2r[ 2] += xv * y0.z;  z2r[ 3] += xv * y0.w;
            z2r[ 4] += xv * y1_.x; z2r[ 5] += xv * y1_.y; z2r[ 6] += xv * y1_.z; z2r[ 7] += xv * y1_.w;
            z2r[ 8] += xv * y2_.x; z2r[ 9] += xv * y2_.y; z2r[10] += xv * y2_.z; z2r[11] += xv * y2_.w;
            z2r[12] += xv * y3_.x; z2r[13] += xv * y3_.y; z2r[14] += xv * y3_.z; z2r[15] += xv * y3_.w;
        }
    }
    __syncthreads();
    float avec[SB];
    #pragma unroll
    for (int i = 0; i < SB; ++i) avec[i] = w3h * z2r[i] * z2r[i];
    #pragma unroll
    for (int i = 0; i < SB; ++i) yT[h][i] = (w3h * 2.f) * z2r[i];
    __syncthreads();

    float tacc[SB];
    #pragma unroll
    for (int i = 0; i < SB; ++i) tacc[i] = 0.f;
    {
        const float* Wc = W2 + h;
        #pragma unroll 4
        for (int k = 0; k < H; ++k) {
            const float wv = Wc[(size_t)k * H];
            const float4 g0  = *reinterpret_cast<const float4*>(&yT[k][0]);
            const float4 g1_ = *reinterpret_cast<const float4*>(&yT[k][4]);
            const float4 g2_ = *reinterpret_cast<const float4*>(&yT[k][8]);
            const float4 g3_ = *reinterpret_cast<const float4*>(&yT[k][12]);
            tacc[ 0] += wv * g0.x;  tacc[ 1] += wv * g0.y;  tacc[ 2] += wv * g0.z;  tacc[ 3] += wv * g0.w;
            tacc[ 4] += wv * g1_.x; tacc[ 5] += wv * g1_.y; tacc[ 6] += wv * g1_.z; tacc[ 7] += wv * g1_.w;
            tacc[ 8] += wv * g2_.x; tacc[ 9] += wv * g2_.y; tacc[10] += wv * g2_.z; tacc[11] += wv * g2_.w;
            tacc[12] += wv * g3_.x; tacc[13] += wv * g3_.y; tacc[14] += wv * g3_.z; tacc[15] += wv * g3_.w;
        }
    }
    const int lane = h & 63;
    const int wid  = h >> 6;
    #pragma unroll
    for (int i = 0; i < SB; ++i) {
        float a = avec[i];
        float b = tacc[i] * p[i];
        #pragma unroll
        for (int off = 32; off; off >>= 1) { a += __shfl_xor(a, off); b += __shfl_xor(b, off); }
        if (lane == 0) { red[wid][i][0] = a; red[wid][i][1] = b; }
    }
    __syncthreads();
    if (h < SB) {
        const int i = h;
        const float nn = red[0][i][0] + red[1][i][0] + red[2][i][0] + red[3][i][0];
        const float gd = red[0][i][1] + red[1][i][1] + red[2][i][1] + red[3][i][1];
        const float c  = csd[i][0];
        const float sd = csd[i][1];
        const int n = s0 + i;
        out[n]         = nn * c;
        out[N + n]     = 2.f * nn * sd + c * gd;
        out[2 * N + n] = c;
    }
}

extern "C" void kernel_launch(void* const* d_in, const int* in_sizes, int n_in,
                              void* d_out, int out_size, void* d_ws, size_t ws_size,
                              hipStream_t stream) {
    const float* S    = (const float*)d_in[0];
    const float* Sdot = (const float*)d_in[1];
    const float* W1   = (const float*)d_in[2];
    const float* b1   = (const float*)d_in[3];
    const float* W2   = (const float*)d_in[4];
    const float* b2   = (const float*)d_in[5];
    const float* W3   = (const float*)d_in[6];
    float* out = (float*)d_out;

    if (ws_size >= 589824) {
        ushort* ws = (ushort*)d_ws;
        prep_weights<<<256, 256, 0, stream>>>(W1, W2, ws);
        fused_mfma<<<N / SB, 256, 0, stream>>>(S, Sdot, b1, b2, W3, ws, out);
    } else {
        float* X = (float*)d_ws;
        transpose_w2<<<H, H, 0, stream>>>(W2, X);
        fused_lyap<<<N / SB, 256, 0, stream>>>(S, Sdot, W1, b1, W2, b2, W3, X, out);
    }
}

// Round 4
// 35.804 us; speedup vs baseline: 30.2516x; 1.0716x over previous
//
#include <hip/hip_runtime.h>

typedef __attribute__((ext_vector_type(8))) short bf16x8;
typedef __attribute__((ext_vector_type(4))) float f32x4;

constexpr int N  = 16384;
constexpr int D  = 64;
constexpr int H  = 256;
constexpr int SB = 64;          // samples per block (4 m-tiles of 16)

__device__ __forceinline__ ushort f2bf(float x) {
    uint u = __float_as_uint(x);
    u += 0x7fffu + ((u >> 16) & 1u);
    return (ushort)(u >> 16);
}
__device__ __forceinline__ float bf2f(ushort h) {
    return __uint_as_float(((uint)h) << 16);
}
// sample-index swizzle within a plane group: bijective, breaks bank aliasing
// of b16 transpose writes (group parity term separates the two h-subgroups
// that share a j/2 bank slot).
__device__ __forceinline__ int swz(int g, int i) {
    return i ^ ((i >> 2) & 3) ^ ((g & 1) << 1);
}

// ---------------------------------------------------------------------------
// d_ws layout (ushort units):
//   B1h @ 0       (16384)   B1l @ 16384      cols c=h1, k=d     (= W1 rows)
//   B2h @ 32768   (65536)   B2l @ 98304      cols c=h2, k=h1    (= W2 rows)
//   B3h @ 163840  (65536)   B3l @ 229376     cols c=h1, k=h2    (= W2^T rows)
// frag layout per plane: flat = ((k>>3)*C + c)*8 + (k&7)
// ---------------------------------------------------------------------------
__global__ void prep_weights(const float* __restrict__ W1, const float* __restrict__ W2,
                             ushort* __restrict__ ws) {
    const int idx = blockIdx.x * 256 + threadIdx.x;   // 0..65535
    {
        const int h2 = idx >> 8, h1 = idx & 255;
        const float x = W2[idx];                      // W2[h2][h1]
        const ushort xh = f2bf(x);
        const ushort xl = f2bf(x - bf2f(xh));
        const int d2 = ((h1 >> 3) * 256 + h2) * 8 + (h1 & 7);
        ws[32768 + d2] = xh;  ws[98304 + d2] = xl;
        const int d3 = ((h2 >> 3) * 256 + h1) * 8 + (h2 & 7);
        ws[163840 + d3] = xh; ws[229376 + d3] = xl;
    }
    if (idx < H * D) {
        const int h1 = idx >> 6, d = idx & 63;
        const float x = W1[idx];                      // W1[h1][d]
        const ushort xh = f2bf(x);
        const ushort xl = f2bf(x - bf2f(xh));
        const int d1 = ((d >> 3) * 256 + h1) * 8 + (d & 7);
        ws[d1] = xh; ws[16384 + d1] = xl;
    }
}

__global__ __launch_bounds__(512, 2) void fused_mfma(
    const float* __restrict__ S,  const float* __restrict__ Sdot,
    const float* __restrict__ b1, const float* __restrict__ b2,
    const float* __restrict__ W3, const ushort* __restrict__ ws,
    float* __restrict__ out)
{
    __shared__ ushort sH[4096], sL[4096], dHp[4096], dLp[4096];  // 8 KB each
    __shared__ ushort yH[16384], yL[16384];                      // 32 KB each
    __shared__ float  red[2][8][64];                             // 4 KB
    __shared__ float  csd[64][2];                                // 0.5 KB

    const int t   = threadIdx.x;
    const int l   = t & 63;
    const int wid = t >> 6;             // wave 0..7, owns h-tiles wid*2, wid*2+1
    const int lg  = l >> 4;
    const int lc  = l & 15;
    const int s0  = blockIdx.x * SB;

    // ---------- stage S/Sdot as split-bf16 planes; fused circle & s.sdot ----
    {
        const int i = t >> 3;           // sample 0..63
        const int g = t & 7;            // d-group of 8
        const float* sp = S    + (size_t)(s0 + i) * D + g * 8;
        const float* dp = Sdot + (size_t)(s0 + i) * D + g * 8;
        const float4 s_a = reinterpret_cast<const float4*>(sp)[0];
        const float4 s_b = reinterpret_cast<const float4*>(sp)[1];
        const float4 d_a = reinterpret_cast<const float4*>(dp)[0];
        const float4 d_b = reinterpret_cast<const float4*>(dp)[1];
        const float sv[8] = {s_a.x,s_a.y,s_a.z,s_a.w,s_b.x,s_b.y,s_b.z,s_b.w};
        const float dv[8] = {d_a.x,d_a.y,d_a.z,d_a.w,d_b.x,d_b.y,d_b.z,d_b.w};
        bf16x8 vsh, vsl, vdh, vdl;
        float c = 0.f, sd = 0.f;
        #pragma unroll
        for (int j = 0; j < 8; ++j) {
            c  += sv[j] * sv[j];
            sd += sv[j] * dv[j];
            const ushort hs = f2bf(sv[j]);
            vsh[j] = (short)hs; vsl[j] = (short)f2bf(sv[j] - bf2f(hs));
            const ushort hd = f2bf(dv[j]);
            vdh[j] = (short)hd; vdl[j] = (short)f2bf(dv[j] - bf2f(hd));
        }
        const int off = (g * 64 + swz(g, i)) * 8;
        *reinterpret_cast<bf16x8*>(&sH [off]) = vsh;
        *reinterpret_cast<bf16x8*>(&sL [off]) = vsl;
        *reinterpret_cast<bf16x8*>(&dHp[off]) = vdh;
        *reinterpret_cast<bf16x8*>(&dLp[off]) = vdl;
        #pragma unroll
        for (int o = 1; o < 8; o <<= 1) { c += __shfl_xor(c, o); sd += __shfl_xor(sd, o); }
        if (g == 0) { csd[i][0] = c; csd[i][1] = sd; }
    }
    __syncthreads();

    // ---------- phase 1: z1 = S@W1^T (+b1 later), u1 = Sdot@W1^T ----------
    f32x4 z1acc[4][2], u1acc[4][2];
    #pragma unroll
    for (int mt = 0; mt < 4; ++mt)
        #pragma unroll
        for (int tt = 0; tt < 2; ++tt) {
            z1acc[mt][tt] = (f32x4){0,0,0,0};
            u1acc[mt][tt] = (f32x4){0,0,0,0};
        }
    {
        const ushort* B1h = ws;
        const ushort* B1l = ws + 16384;
        #pragma unroll
        for (int kc = 0; kc < 2; ++kc) {
            const int grp = kc * 4 + lg;
            bf16x8 ash[4], asl[4], adh[4], adl[4];
            #pragma unroll
            for (int mt = 0; mt < 4; ++mt) {
                const int off = (grp * 64 + swz(grp, mt * 16 + lc)) * 8;
                ash[mt] = *reinterpret_cast<const bf16x8*>(&sH [off]);
                asl[mt] = *reinterpret_cast<const bf16x8*>(&sL [off]);
                adh[mt] = *reinterpret_cast<const bf16x8*>(&dHp[off]);
                adl[mt] = *reinterpret_cast<const bf16x8*>(&dLp[off]);
            }
            #pragma unroll
            for (int tt = 0; tt < 2; ++tt) {
                const int h    = (wid * 2 + tt) * 16 + lc;
                const int boff = (grp * 256 + h) * 8;
                const bf16x8 bh = *reinterpret_cast<const bf16x8*>(B1h + boff);
                const bf16x8 bl = *reinterpret_cast<const bf16x8*>(B1l + boff);
                #pragma unroll
                for (int mt = 0; mt < 4; ++mt) {
                    z1acc[mt][tt] = __builtin_amdgcn_mfma_f32_16x16x32_bf16(ash[mt], bh, z1acc[mt][tt], 0,0,0);
                    z1acc[mt][tt] = __builtin_amdgcn_mfma_f32_16x16x32_bf16(asl[mt], bh, z1acc[mt][tt], 0,0,0);
                    z1acc[mt][tt] = __builtin_amdgcn_mfma_f32_16x16x32_bf16(ash[mt], bl, z1acc[mt][tt], 0,0,0);
                    u1acc[mt][tt] = __builtin_amdgcn_mfma_f32_16x16x32_bf16(adh[mt], bh, u1acc[mt][tt], 0,0,0);
                    u1acc[mt][tt] = __builtin_amdgcn_mfma_f32_16x16x32_bf16(adl[mt], bh, u1acc[mt][tt], 0,0,0);
                    u1acc[mt][tt] = __builtin_amdgcn_mfma_f32_16x16x32_bf16(adh[mt], bl, u1acc[mt][tt], 0,0,0);
                }
            }
        }
    }

    // D layout: sample row = mt*16 + lg*4 + r, col h = (wid*2+tt)*16 + lc
    // publish y1 = (z1+b1)^2 split-bf16; keep p = 2*z1*u1 in registers
    f32x4 p[4][2];
    #pragma unroll
    for (int tt = 0; tt < 2; ++tt) {
        const int h   = (wid * 2 + tt) * 16 + lc;
        const float bb = b1[h];
        const int grp = h >> 3;
        const int jb  = grp * 512 + (h & 7);
        #pragma unroll
        for (int mt = 0; mt < 4; ++mt) {
            #pragma unroll
            for (int r = 0; r < 4; ++r) {
                const float z = z1acc[mt][tt][r] + bb;
                p[mt][tt][r] = 2.f * z * u1acc[mt][tt][r];
                const float y   = z * z;
                const ushort yh = f2bf(y);
                const ushort yl = f2bf(y - bf2f(yh));
                const int ii = swz(grp, mt * 16 + lg * 4 + r);
                yH[jb + ii * 8] = yh;
                yL[jb + ii * 8] = yl;
            }
        }
    }
    __syncthreads();

    // ---------- phase 2: z2 = y1 @ W2^T ----------
    f32x4 z2acc[4][2];
    #pragma unroll
    for (int mt = 0; mt < 4; ++mt)
        #pragma unroll
        for (int tt = 0; tt < 2; ++tt) z2acc[mt][tt] = (f32x4){0,0,0,0};
    {
        const ushort* B2h = ws + 32768;
        const ushort* B2l = ws + 98304;
        #pragma unroll 2
        for (int kc = 0; kc < 8; ++kc) {
            const int grp = kc * 4 + lg;
            bf16x8 ah[4], al[4];
            #pragma unroll
            for (int mt = 0; mt < 4; ++mt) {
                const int off = (grp * 64 + swz(grp, mt * 16 + lc)) * 8;
                ah[mt] = *reinterpret_cast<const bf16x8*>(&yH[off]);
                al[mt] = *reinterpret_cast<const bf16x8*>(&yL[off]);
            }
            #pragma unroll
            for (int tt = 0; tt < 2; ++tt) {
                const int h    = (wid * 2 + tt) * 16 + lc;
                const int boff = (grp * 256 + h) * 8;
                const bf16x8 bh = *reinterpret_cast<const bf16x8*>(B2h + boff);
                const bf16x8 bl = *reinterpret_cast<const bf16x8*>(B2l + boff);
                #pragma unroll
                for (int mt = 0; mt < 4; ++mt) {
                    z2acc[mt][tt] = __builtin_amdgcn_mfma_f32_16x16x32_bf16(ah[mt], bh, z2acc[mt][tt], 0,0,0);
                    z2acc[mt][tt] = __builtin_amdgcn_mfma_f32_16x16x32_bf16(al[mt], bh, z2acc[mt][tt], 0,0,0);
                    z2acc[mt][tt] = __builtin_amdgcn_mfma_f32_16x16x32_bf16(ah[mt], bl, z2acc[mt][tt], 0,0,0);
                }
            }
        }
    }
    __syncthreads();   // all waves done READING y1 before g2 overwrite

    // nn partials; publish g2 = 2*W3*z2 split-bf16
    float nnp[4][4];
    #pragma unroll
    for (int mt = 0; mt < 4; ++mt)
        #pragma unroll
        for (int r = 0; r < 4; ++r) nnp[mt][r] = 0.f;
    #pragma unroll
    for (int tt = 0; tt < 2; ++tt) {
        const int h    = (wid * 2 + tt) * 16 + lc;
        const float bb = b2[h];
        const float w3 = W3[h];
        const int grp = h >> 3;
        const int jb  = grp * 512 + (h & 7);
        #pragma unroll
        for (int mt = 0; mt < 4; ++mt) {
            #pragma unroll
            for (int r = 0; r < 4; ++r) {
                const float z = z2acc[mt][tt][r] + bb;
                nnp[mt][r] += w3 * z * z;
                const float gv  = 2.f * w3 * z;
                const ushort gh = f2bf(gv);
                const ushort gl = f2bf(gv - bf2f(gh));
                const int ii = swz(grp, mt * 16 + lg * 4 + r);
                yH[jb + ii * 8] = gh;
                yL[jb + ii * 8] = gl;
            }
        }
    }
    #pragma unroll
    for (int mt = 0; mt < 4; ++mt)
        #pragma unroll
        for (int r = 0; r < 4; ++r) {
            float v = nnp[mt][r];
            #pragma unroll
            for (int o = 1; o < 16; o <<= 1) v += __shfl_xor(v, o);
            if (lc == 0) red[0][wid][mt * 16 + lg * 4 + r] = v;
        }
    __syncthreads();   // g2 planes + red[0] visible

    // ---------- phase 3: t = g2 @ W2 ----------
    f32x4 tacc[4][2];
    #pragma unroll
    for (int mt = 0; mt < 4; ++mt)
        #pragma unroll
        for (int tt = 0; tt < 2; ++tt) tacc[mt][tt] = (f32x4){0,0,0,0};
    {
        const ushort* B3h = ws + 163840;
        const ushort* B3l = ws + 229376;
        #pragma unroll 2
        for (int kc = 0; kc < 8; ++kc) {
            const int grp = kc * 4 + lg;
            bf16x8 ah[4], al[4];
            #pragma unroll
            for (int mt = 0; mt < 4; ++mt) {
                const int off = (grp * 64 + swz(grp, mt * 16 + lc)) * 8;
                ah[mt] = *reinterpret_cast<const bf16x8*>(&yH[off]);
                al[mt] = *reinterpret_cast<const bf16x8*>(&yL[off]);
            }
            #pragma unroll
            for (int tt = 0; tt < 2; ++tt) {
                const int h    = (wid * 2 + tt) * 16 + lc;
                const int boff = (grp * 256 + h) * 8;
                const bf16x8 bh = *reinterpret_cast<const bf16x8*>(B3h + boff);
                const bf16x8 bl = *reinterpret_cast<const bf16x8*>(B3l + boff);
                #pragma unroll
                for (int mt = 0; mt < 4; ++mt) {
                    tacc[mt][tt] = __builtin_amdgcn_mfma_f32_16x16x32_bf16(ah[mt], bh, tacc[mt][tt], 0,0,0);
                    tacc[mt][tt] = __builtin_amdgcn_mfma_f32_16x16x32_bf16(al[mt], bh, tacc[mt][tt], 0,0,0);
                    tacc[mt][tt] = __builtin_amdgcn_mfma_f32_16x16x32_bf16(ah[mt], bl, tacc[mt][tt], 0,0,0);
                }
            }
        }
    }
    #pragma unroll
    for (int mt = 0; mt < 4; ++mt)
        #pragma unroll
        for (int r = 0; r < 4; ++r) {
            float v = tacc[mt][0][r] * p[mt][0][r] + tacc[mt][1][r] * p[mt][1][r];
            #pragma unroll
            for (int o = 1; o < 16; o <<= 1) v += __shfl_xor(v, o);
            if (lc == 0) red[1][wid][mt * 16 + lg * 4 + r] = v;
        }
    __syncthreads();

    // ---------- finalize ----------
    if (t < SB) {
        const int i = t;
        float nn = 0.f, gd = 0.f;
        #pragma unroll
        for (int w = 0; w < 8; ++w) { nn += red[0][w][i]; gd += red[1][w][i]; }
        const float c  = csd[i][0];
        const float sd = csd[i][1];
        const int n = s0 + i;
        out[n]         = nn * c;                 // V
        out[N + n]     = 2.f * nn * sd + c * gd; // Vdot
        out[2 * N + n] = c;                      // circle
    }
}

extern "C" void kernel_launch(void* const* d_in, const int* in_sizes, int n_in,
                              void* d_out, int out_size, void* d_ws, size_t ws_size,
                              hipStream_t stream) {
    const float* S    = (const float*)d_in[0];
    const float* Sdot = (const float*)d_in[1];
    const float* W1   = (const float*)d_in[2];
    const float* b1   = (const float*)d_in[3];
    const float* W2   = (const float*)d_in[4];
    const float* b2   = (const float*)d_in[5];
    const float* W3   = (const float*)d_in[6];
    float* out = (float*)d_out;
    ushort* ws = (ushort*)d_ws;    // 576 KB weight planes

    prep_weights<<<256, 256, 0, stream>>>(W1, W2, ws);
    fused_mfma<<<N / SB, 512, 0, stream>>>(S, Sdot, b1, b2, W3, ws, out);
}

// Round 5
// 29.189 us; speedup vs baseline: 37.1072x; 1.2266x over previous
//
#include <hip/hip_runtime.h>

typedef __attribute__((ext_vector_type(8))) short bf16x8;
typedef __attribute__((ext_vector_type(4))) float f32x4;

constexpr int N  = 16384;
constexpr int D  = 64;
constexpr int H  = 256;
constexpr int SB = 64;          // samples per block (4 m-tiles of 16)

__device__ __forceinline__ ushort f2bf(float x) {
    uint u = __float_as_uint(x);
    u += 0x7fffu + ((u >> 16) & 1u);
    return (ushort)(u >> 16);
}
__device__ __forceinline__ float bf2f(ushort h) {
    return __uint_as_float(((uint)h) << 16);
}
// sample-index swizzle within a plane group: bijective, breaks bank aliasing
// of the b16 transpose writes.
__device__ __forceinline__ int swz(int g, int i) {
    return i ^ ((i >> 2) & 3) ^ ((g & 1) << 1);
}

// ---------------------------------------------------------------------------
// d_ws layout (ushort units):
//   B1h @ 0       (16384)   B1l @ 16384      cols c=h1, k=d     (= W1 rows)
//   B2h @ 32768   (65536)   B2l @ 98304      cols c=h2, k=h1    (= W2 rows)
// frag layout per plane: flat = ((k>>3)*C + c)*8 + (k&7)
// total 163840 ushorts = 320 KB.  (B3 no longer needed: gd via q = p @ W2^T)
// ---------------------------------------------------------------------------
__global__ void prep_weights(const float* __restrict__ W1, const float* __restrict__ W2,
                             ushort* __restrict__ ws) {
    const int t = blockIdx.x * 256 + threadIdx.x;    // 0..10239
    if (t < 8192) {                                  // B2 planes
        const int h1g = t >> 8;                      // k-group 0..31
        const int h2  = t & 255;                     // minor -> coalesced writes
        const float* src = W2 + h2 * 256 + h1g * 8;
        bf16x8 hi, lo;
        #pragma unroll
        for (int j = 0; j < 8; ++j) {
            const float x = src[j];
            const ushort xh = f2bf(x);
            hi[j] = (short)xh;
            lo[j] = (short)f2bf(x - bf2f(xh));
        }
        const int d2 = (h1g * 256 + h2) * 8;
        *reinterpret_cast<bf16x8*>(ws + 32768 + d2) = hi;
        *reinterpret_cast<bf16x8*>(ws + 98304 + d2) = lo;
    } else if (t < 10240) {                          // B1 planes
        const int u  = t - 8192;
        const int dg = u >> 8;                       // k-group 0..7
        const int h1 = u & 255;
        const float* src = W1 + h1 * 64 + dg * 8;
        bf16x8 hi, lo;
        #pragma unroll
        for (int j = 0; j < 8; ++j) {
            const float x = src[j];
            const ushort xh = f2bf(x);
            hi[j] = (short)xh;
            lo[j] = (short)f2bf(x - bf2f(xh));
        }
        const int d1 = (dg * 256 + h1) * 8;
        *reinterpret_cast<bf16x8*>(ws + d1)         = hi;
        *reinterpret_cast<bf16x8*>(ws + 16384 + d1) = lo;
    }
}

__global__ __launch_bounds__(512, 2) void fused_mfma(
    const float* __restrict__ S,  const float* __restrict__ Sdot,
    const float* __restrict__ b1v, const float* __restrict__ b2v,
    const float* __restrict__ W3, const ushort* __restrict__ ws,
    float* __restrict__ out)
{
    __shared__ ushort U[65536];          // 128 KB, regions below
    __shared__ float  red[2][8][64];     // 4 KB
    __shared__ float  csd[64][2];        // 0.5 KB

    ushort* const sH = U;                // 4096 each: S/Sdot split planes
    ushort* const sL = U + 4096;
    ushort* const dH = U + 8192;
    ushort* const dL = U + 12288;
    ushort* const pH = U;                // ALIAS: reuses S region after phase 1
    ushort* const yH = U + 16384;        // 16384 each: y1 / p planes
    ushort* const yL = U + 32768;
    ushort* const pL = U + 49152;

    const int t   = threadIdx.x;
    const int l   = t & 63;
    const int wid = t >> 6;              // wave 0..7 owns h-tiles wid*2(+1)
    const int lg  = l >> 4;
    const int lc  = l & 15;
    const int s0  = blockIdx.x * SB;

    const int hA = (wid * 2 + 0) * 16 + lc;
    const int hB = (wid * 2 + 1) * 16 + lc;

    // ---------- hoisted weight fragments (issued before any barrier) ----------
    bf16x8 B1h[2][2], B1l[2][2];
    #pragma unroll
    for (int kc = 0; kc < 2; ++kc) {
        const int g  = kc * 4 + lg;
        const int o0 = (g * 256 + hA) * 8;
        const int o1 = (g * 256 + hB) * 8;
        B1h[kc][0] = *reinterpret_cast<const bf16x8*>(ws + o0);
        B1h[kc][1] = *reinterpret_cast<const bf16x8*>(ws + o1);
        B1l[kc][0] = *reinterpret_cast<const bf16x8*>(ws + 16384 + o0);
        B1l[kc][1] = *reinterpret_cast<const bf16x8*>(ws + 16384 + o1);
    }
    bf16x8 nbh[2], nbl[2];               // phase-2 kc=0 B2 prefetch
    {
        const int o0 = (lg * 256 + hA) * 8;
        const int o1 = (lg * 256 + hB) * 8;
        nbh[0] = *reinterpret_cast<const bf16x8*>(ws + 32768 + o0);
        nbh[1] = *reinterpret_cast<const bf16x8*>(ws + 32768 + o1);
        nbl[0] = *reinterpret_cast<const bf16x8*>(ws + 98304 + o0);
        nbl[1] = *reinterpret_cast<const bf16x8*>(ws + 98304 + o1);
    }
    const float bb1[2] = { b1v[hA], b1v[hB] };
    const float bb2[2] = { b2v[hA], b2v[hB] };
    const float w3v[2] = { W3[hA],  W3[hB]  };

    // ---------- stage S/Sdot as split-bf16 planes; fused circle & s.sdot ----
    {
        const int i = t >> 3;            // sample 0..63
        const int g = t & 7;             // d-group of 8
        const float* sp = S    + (size_t)(s0 + i) * D + g * 8;
        const float* dp = Sdot + (size_t)(s0 + i) * D + g * 8;
        const float4 s_a = reinterpret_cast<const float4*>(sp)[0];
        const float4 s_b = reinterpret_cast<const float4*>(sp)[1];
        const float4 d_a = reinterpret_cast<const float4*>(dp)[0];
        const float4 d_b = reinterpret_cast<const float4*>(dp)[1];
        const float sv[8] = {s_a.x,s_a.y,s_a.z,s_a.w,s_b.x,s_b.y,s_b.z,s_b.w};
        const float dv[8] = {d_a.x,d_a.y,d_a.z,d_a.w,d_b.x,d_b.y,d_b.z,d_b.w};
        bf16x8 vsh, vsl, vdh, vdl;
        float c = 0.f, sd = 0.f;
        #pragma unroll
        for (int j = 0; j < 8; ++j) {
            c  += sv[j] * sv[j];
            sd += sv[j] * dv[j];
            const ushort hs = f2bf(sv[j]);
            vsh[j] = (short)hs; vsl[j] = (short)f2bf(sv[j] - bf2f(hs));
            const ushort hd = f2bf(dv[j]);
            vdh[j] = (short)hd; vdl[j] = (short)f2bf(dv[j] - bf2f(hd));
        }
        const int off = (g * 64 + swz(g, i)) * 8;
        *reinterpret_cast<bf16x8*>(&sH[off]) = vsh;
        *reinterpret_cast<bf16x8*>(&sL[off]) = vsl;
        *reinterpret_cast<bf16x8*>(&dH[off]) = vdh;
        *reinterpret_cast<bf16x8*>(&dL[off]) = vdl;
        #pragma unroll
        for (int o = 1; o < 8; o <<= 1) { c += __shfl_xor(c, o); sd += __shfl_xor(sd, o); }
        if (g == 0) { csd[i][0] = c; csd[i][1] = sd; }
    }
    __syncthreads();                                 // (1) staging visible

    // ---------- phase 1: z1 = S@W1^T, u1 = Sdot@W1^T ----------
    f32x4 z1acc[4][2], u1acc[4][2];
    #pragma unroll
    for (int mt = 0; mt < 4; ++mt)
        #pragma unroll
        for (int tt = 0; tt < 2; ++tt) {
            z1acc[mt][tt] = (f32x4){0,0,0,0};
            u1acc[mt][tt] = (f32x4){0,0,0,0};
        }
    #pragma unroll
    for (int kc = 0; kc < 2; ++kc) {
        const int g = kc * 4 + lg;
        bf16x8 ash[4], asl[4], adh[4], adl[4];
        #pragma unroll
        for (int mt = 0; mt < 4; ++mt) {
            const int off = (g * 64 + swz(g, mt * 16 + lc)) * 8;
            ash[mt] = *reinterpret_cast<const bf16x8*>(&sH[off]);
            asl[mt] = *reinterpret_cast<const bf16x8*>(&sL[off]);
            adh[mt] = *reinterpret_cast<const bf16x8*>(&dH[off]);
            adl[mt] = *reinterpret_cast<const bf16x8*>(&dL[off]);
        }
        #pragma unroll
        for (int tt = 0; tt < 2; ++tt) {
            #pragma unroll
            for (int mt = 0; mt < 4; ++mt) {
                z1acc[mt][tt] = __builtin_amdgcn_mfma_f32_16x16x32_bf16(ash[mt], B1h[kc][tt], z1acc[mt][tt], 0,0,0);
                z1acc[mt][tt] = __builtin_amdgcn_mfma_f32_16x16x32_bf16(asl[mt], B1h[kc][tt], z1acc[mt][tt], 0,0,0);
                z1acc[mt][tt] = __builtin_amdgcn_mfma_f32_16x16x32_bf16(ash[mt], B1l[kc][tt], z1acc[mt][tt], 0,0,0);
                u1acc[mt][tt] = __builtin_amdgcn_mfma_f32_16x16x32_bf16(adh[mt], B1h[kc][tt], u1acc[mt][tt], 0,0,0);
                u1acc[mt][tt] = __builtin_amdgcn_mfma_f32_16x16x32_bf16(adl[mt], B1h[kc][tt], u1acc[mt][tt], 0,0,0);
                u1acc[mt][tt] = __builtin_amdgcn_mfma_f32_16x16x32_bf16(adh[mt], B1l[kc][tt], u1acc[mt][tt], 0,0,0);
            }
        }
    }

    // D layout: sample row = mt*16 + lg*4 + r, col h = (wid*2+tt)*16 + lc
    // publish y1 = (z1+b1)^2 (split) and p-lo now; p-hi after the alias barrier
    f32x4 p_[4][2];
    #pragma unroll
    for (int tt = 0; tt < 2; ++tt) {
        const int h   = (wid * 2 + tt) * 16 + lc;
        const int grp = h >> 3;
        const int jb  = grp * 512 + (h & 7);
        #pragma unroll
        for (int mt = 0; mt < 4; ++mt) {
            #pragma unroll
            for (int r = 0; r < 4; ++r) {
                const float z = z1acc[mt][tt][r] + bb1[tt];
                const float pv = 2.f * z * u1acc[mt][tt][r];
                p_[mt][tt][r] = pv;
                const float y   = z * z;
                const ushort yh = f2bf(y);
                const ushort yl = f2bf(y - bf2f(yh));
                const ushort ph = f2bf(pv);
                const ushort pl = f2bf(pv - bf2f(ph));
                const int ii = swz(grp, mt * 16 + lg * 4 + r);
                yH[jb + ii * 8] = yh;
                yL[jb + ii * 8] = yl;
                pL[jb + ii * 8] = pl;
            }
        }
    }
    __syncthreads();                                 // (2) all S-reads done; y/pL visible

    // publish p-hi into the (dead) S region
    #pragma unroll
    for (int tt = 0; tt < 2; ++tt) {
        const int h   = (wid * 2 + tt) * 16 + lc;
        const int grp = h >> 3;
        const int jb  = grp * 512 + (h & 7);
        #pragma unroll
        for (int mt = 0; mt < 4; ++mt) {
            #pragma unroll
            for (int r = 0; r < 4; ++r) {
                const int ii = swz(grp, mt * 16 + lg * 4 + r);
                pH[jb + ii * 8] = f2bf(p_[mt][tt][r]);
            }
        }
    }
    __syncthreads();                                 // (3) pH visible

    // ---------- merged phase 2: z2 = y1@W2^T  AND  q = p@W2^T ----------
    f32x4 z2acc[4][2], qacc[4][2];
    #pragma unroll
    for (int mt = 0; mt < 4; ++mt)
        #pragma unroll
        for (int tt = 0; tt < 2; ++tt) {
            z2acc[mt][tt] = (f32x4){0,0,0,0};
            qacc[mt][tt]  = (f32x4){0,0,0,0};
        }
    #pragma unroll 2
    for (int kc = 0; kc < 8; ++kc) {
        const int g = kc * 4 + lg;
        const bf16x8 bh0 = nbh[0], bh1 = nbh[1];
        const bf16x8 bl0 = nbl[0], bl1 = nbl[1];
        if (kc < 7) {                                // rotate: prefetch kc+1 B2 frags
            const int gn = (kc + 1) * 4 + lg;
            const int o0 = (gn * 256 + hA) * 8;
            const int o1 = (gn * 256 + hB) * 8;
            nbh[0] = *reinterpret_cast<const bf16x8*>(ws + 32768 + o0);
            nbh[1] = *reinterpret_cast<const bf16x8*>(ws + 32768 + o1);
            nbl[0] = *reinterpret_cast<const bf16x8*>(ws + 98304 + o0);
            nbl[1] = *reinterpret_cast<const bf16x8*>(ws + 98304 + o1);
        }
        bf16x8 ayh[4], ayl[4], aph[4], apl[4];
        #pragma unroll
        for (int mt = 0; mt < 4; ++mt) {
            const int off = (g * 64 + swz(g, mt * 16 + lc)) * 8;
            ayh[mt] = *reinterpret_cast<const bf16x8*>(&yH[off]);
            ayl[mt] = *reinterpret_cast<const bf16x8*>(&yL[off]);
            aph[mt] = *reinterpret_cast<const bf16x8*>(&pH[off]);
            apl[mt] = *reinterpret_cast<const bf16x8*>(&pL[off]);
        }
        #pragma unroll
        for (int mt = 0; mt < 4; ++mt) {
            z2acc[mt][0] = __builtin_amdgcn_mfma_f32_16x16x32_bf16(ayh[mt], bh0, z2acc[mt][0], 0,0,0);
            z2acc[mt][0] = __builtin_amdgcn_mfma_f32_16x16x32_bf16(ayl[mt], bh0, z2acc[mt][0], 0,0,0);
            z2acc[mt][0] = __builtin_amdgcn_mfma_f32_16x16x32_bf16(ayh[mt], bl0, z2acc[mt][0], 0,0,0);
            qacc[mt][0]  = __builtin_amdgcn_mfma_f32_16x16x32_bf16(aph[mt], bh0, qacc[mt][0], 0,0,0);
            qacc[mt][0]  = __builtin_amdgcn_mfma_f32_16x16x32_bf16(apl[mt], bh0, qacc[mt][0], 0,0,0);
            qacc[mt][0]  = __builtin_amdgcn_mfma_f32_16x16x32_bf16(aph[mt], bl0, qacc[mt][0], 0,0,0);
            z2acc[mt][1] = __builtin_amdgcn_mfma_f32_16x16x32_bf16(ayh[mt], bh1, z2acc[mt][1], 0,0,0);
            z2acc[mt][1] = __builtin_amdgcn_mfma_f32_16x16x32_bf16(ayl[mt], bh1, z2acc[mt][1], 0,0,0);
            z2acc[mt][1] = __builtin_amdgcn_mfma_f32_16x16x32_bf16(ayh[mt], bl1, z2acc[mt][1], 0,0,0);
            qacc[mt][1]  = __builtin_amdgcn_mfma_f32_16x16x32_bf16(aph[mt], bh1, qacc[mt][1], 0,0,0);
            qacc[mt][1]  = __builtin_amdgcn_mfma_f32_16x16x32_bf16(apl[mt], bh1, qacc[mt][1], 0,0,0);
            qacc[mt][1]  = __builtin_amdgcn_mfma_f32_16x16x32_bf16(aph[mt], bl1, qacc[mt][1], 0,0,0);
        }
    }

    // ---------- epilogue: nn = sum w3*(z2+b2)^2 ; gd = sum 2*w3*(z2+b2)*q ----
    float nnp[4][4], gdp[4][4];
    #pragma unroll
    for (int mt = 0; mt < 4; ++mt)
        #pragma unroll
        for (int r = 0; r < 4; ++r) { nnp[mt][r] = 0.f; gdp[mt][r] = 0.f; }
    #pragma unroll
    for (int tt = 0; tt < 2; ++tt) {
        #pragma unroll
        for (int mt = 0; mt < 4; ++mt) {
            #pragma unroll
            for (int r = 0; r < 4; ++r) {
                const float z = z2acc[mt][tt][r] + bb2[tt];
                nnp[mt][r] += w3v[tt] * z * z;
                gdp[mt][r] += 2.f * w3v[tt] * z * qacc[mt][tt][r];
            }
        }
    }
    #pragma unroll
    for (int mt = 0; mt < 4; ++mt)
        #pragma unroll
        for (int r = 0; r < 4; ++r) {
            float a = nnp[mt][r], b = gdp[mt][r];
            #pragma unroll
            for (int o = 1; o < 16; o <<= 1) { a += __shfl_xor(a, o); b += __shfl_xor(b, o); }
            if (lc == 0) {
                red[0][wid][mt * 16 + lg * 4 + r] = a;
                red[1][wid][mt * 16 + lg * 4 + r] = b;
            }
        }
    __syncthreads();                                 // (4) red visible

    // ---------- finalize ----------
    if (t < SB) {
        const int i = t;
        float nn = 0.f, gd = 0.f;
        #pragma unroll
        for (int w = 0; w < 8; ++w) { nn += red[0][w][i]; gd += red[1][w][i]; }
        const float c  = csd[i][0];
        const float sd = csd[i][1];
        const int n = s0 + i;
        out[n]         = nn * c;                 // V
        out[N + n]     = 2.f * nn * sd + c * gd; // Vdot
        out[2 * N + n] = c;                      // circle
    }
}

extern "C" void kernel_launch(void* const* d_in, const int* in_sizes, int n_in,
                              void* d_out, int out_size, void* d_ws, size_t ws_size,
                              hipStream_t stream) {
    const float* S    = (const float*)d_in[0];
    const float* Sdot = (const float*)d_in[1];
    const float* W1   = (const float*)d_in[2];
    const float* b1   = (const float*)d_in[3];
    const float* W2   = (const float*)d_in[4];
    const float* b2   = (const float*)d_in[5];
    const float* W3   = (const float*)d_in[6];
    float* out = (float*)d_out;
    ushort* ws = (ushort*)d_ws;    // 320 KB weight planes

    prep_weights<<<40, 256, 0, stream>>>(W1, W2, ws);
    fused_mfma<<<N / SB, 512, 0, stream>>>(S, Sdot, b1, b2, W3, ws, out);
}

// Round 6
// 26.541 us; speedup vs baseline: 40.8086x; 1.0997x over previous
//
#include <hip/hip_runtime.h>

typedef __attribute__((ext_vector_type(8))) short bf16x8;
typedef __attribute__((ext_vector_type(4))) float f32x4;

constexpr int N  = 16384;
constexpr int D  = 64;
constexpr int H  = 256;
constexpr int SB = 32;           // samples per block (2 m-tiles), 2 blocks/CU
constexpr int PITCH = 272;       // ushorts per k-group row: 32*8 + 16 pad
                                 // (544 B stride == 8 banks shift per group)

__device__ __forceinline__ ushort f2bf(float x) {
    uint u = __float_as_uint(x);
    u += 0x7fffu + ((u >> 16) & 1u);
    return (ushort)(u >> 16);
}
__device__ __forceinline__ float bf2f(ushort h) {
    return __uint_as_float(((uint)h) << 16);
}
// bijective sample swizzle within each 16-block
__device__ __forceinline__ int swz(int g, int i) {
    return i ^ ((i >> 2) & 3) ^ ((g & 1) << 1);
}

// ---------------------------------------------------------------------------
// d_ws layout (ushort units):
//   B1h @ 0       (16384)   B1l @ 16384      cols c=h1, k=d     (= W1 rows)
//   B2h @ 32768   (65536)   B2l @ 98304      cols c=h2, k=h1    (= W2 rows)
// frag layout per plane: flat = ((k>>3)*256 + c)*8 + (k&7);  320 KB total
// ---------------------------------------------------------------------------
__global__ void prep_weights(const float* __restrict__ W1, const float* __restrict__ W2,
                             ushort* __restrict__ ws) {
    const int t = blockIdx.x * 256 + threadIdx.x;    // 0..10239
    if (t < 8192) {                                  // B2 planes
        const int h1g = t >> 8;                      // k-group 0..31
        const int h2  = t & 255;                     // minor -> coalesced writes
        const float* src = W2 + h2 * 256 + h1g * 8;
        bf16x8 hi, lo;
        #pragma unroll
        for (int j = 0; j < 8; ++j) {
            const float x = src[j];
            const ushort xh = f2bf(x);
            hi[j] = (short)xh;
            lo[j] = (short)f2bf(x - bf2f(xh));
        }
        const int d2 = (h1g * 256 + h2) * 8;
        *reinterpret_cast<bf16x8*>(ws + 32768 + d2) = hi;
        *reinterpret_cast<bf16x8*>(ws + 98304 + d2) = lo;
    } else if (t < 10240) {                          // B1 planes
        const int u  = t - 8192;
        const int dg = u >> 8;                       // k-group 0..7
        const int h1 = u & 255;
        const float* src = W1 + h1 * 64 + dg * 8;
        bf16x8 hi, lo;
        #pragma unroll
        for (int j = 0; j < 8; ++j) {
            const float x = src[j];
            const ushort xh = f2bf(x);
            hi[j] = (short)xh;
            lo[j] = (short)f2bf(x - bf2f(xh));
        }
        const int d1 = (dg * 256 + h1) * 8;
        *reinterpret_cast<bf16x8*>(ws + d1)         = hi;
        *reinterpret_cast<bf16x8*>(ws + 16384 + d1) = lo;
    }
}

__global__ __launch_bounds__(256, 2) void fused_mfma(
    const float* __restrict__ S,  const float* __restrict__ Sdot,
    const float* __restrict__ b1v, const float* __restrict__ b2v,
    const float* __restrict__ W3, const ushort* __restrict__ ws,
    float* __restrict__ out)
{
    __shared__ ushort U[34816];          // 68 KB
    __shared__ float  red[2][4][32];     // 1 KB
    __shared__ float  csd[32][2];

    ushort* const sH = U;                // 2176 each (8 groups * PITCH)
    ushort* const sL = U + 2176;
    ushort* const dH = U + 4352;
    ushort* const dL = U + 6528;
    ushort* const pH = U;                // ALIAS: 8704 (32 groups * PITCH), after phase 1
    ushort* const yH = U + 8704;
    ushort* const yL = U + 17408;
    ushort* const pL = U + 26112;

    const int t   = threadIdx.x;
    const int l   = t & 63;
    const int wid = t >> 6;              // wave 0..3, owns h-tiles wid*4 .. wid*4+3
    const int lg  = l >> 4;
    const int lc  = l & 15;
    const int s0  = blockIdx.x * SB;

    int hh[4];
    #pragma unroll
    for (int tt = 0; tt < 4; ++tt) hh[tt] = (wid * 4 + tt) * 16 + lc;

    // ---------- hoisted weight fragments (before any barrier) ----------
    bf16x8 B1h[2][4], B1l[2][4];
    #pragma unroll
    for (int kc = 0; kc < 2; ++kc) {
        const int g = kc * 4 + lg;
        #pragma unroll
        for (int tt = 0; tt < 4; ++tt) {
            const int o = (g * 256 + hh[tt]) * 8;
            B1h[kc][tt] = *reinterpret_cast<const bf16x8*>(ws + o);
            B1l[kc][tt] = *reinterpret_cast<const bf16x8*>(ws + 16384 + o);
        }
    }
    bf16x8 nbh[4], nbl[4];               // phase-2 kc=0 B2 prefetch
    #pragma unroll
    for (int tt = 0; tt < 4; ++tt) {
        const int o = (lg * 256 + hh[tt]) * 8;
        nbh[tt] = *reinterpret_cast<const bf16x8*>(ws + 32768 + o);
        nbl[tt] = *reinterpret_cast<const bf16x8*>(ws + 98304 + o);
    }
    float bb1[4], bb2[4], w3v[4];
    #pragma unroll
    for (int tt = 0; tt < 4; ++tt) {
        bb1[tt] = b1v[hh[tt]]; bb2[tt] = b2v[hh[tt]]; w3v[tt] = W3[hh[tt]];
    }

    // ---------- stage S/Sdot as split-bf16 planes; fused circle & s.sdot ----
    {
        const int i = t >> 3;            // sample 0..31
        const int g = t & 7;             // d-group
        const float* sp = S    + (size_t)(s0 + i) * D + g * 8;
        const float* dp = Sdot + (size_t)(s0 + i) * D + g * 8;
        const float4 s_a = reinterpret_cast<const float4*>(sp)[0];
        const float4 s_b = reinterpret_cast<const float4*>(sp)[1];
        const float4 d_a = reinterpret_cast<const float4*>(dp)[0];
        const float4 d_b = reinterpret_cast<const float4*>(dp)[1];
        const float sv[8] = {s_a.x,s_a.y,s_a.z,s_a.w,s_b.x,s_b.y,s_b.z,s_b.w};
        const float dv[8] = {d_a.x,d_a.y,d_a.z,d_a.w,d_b.x,d_b.y,d_b.z,d_b.w};
        bf16x8 vsh, vsl, vdh, vdl;
        float c = 0.f, sd = 0.f;
        #pragma unroll
        for (int j = 0; j < 8; ++j) {
            c  += sv[j] * sv[j];
            sd += sv[j] * dv[j];
            const ushort hs = f2bf(sv[j]);
            vsh[j] = (short)hs; vsl[j] = (short)f2bf(sv[j] - bf2f(hs));
            const ushort hd = f2bf(dv[j]);
            vdh[j] = (short)hd; vdl[j] = (short)f2bf(dv[j] - bf2f(hd));
        }
        const int off = g * PITCH + swz(g, i) * 8;
        *reinterpret_cast<bf16x8*>(&sH[off]) = vsh;
        *reinterpret_cast<bf16x8*>(&sL[off]) = vsl;
        *reinterpret_cast<bf16x8*>(&dH[off]) = vdh;
        *reinterpret_cast<bf16x8*>(&dL[off]) = vdl;
        #pragma unroll
        for (int o = 1; o < 8; o <<= 1) { c += __shfl_xor(c, o); sd += __shfl_xor(sd, o); }
        if (g == 0) { csd[i][0] = c; csd[i][1] = sd; }
    }
    __syncthreads();                                 // (1) staging visible

    // ---------- phase 1: z1 = S@W1^T, u1 = Sdot@W1^T ----------
    f32x4 z1acc[2][4], u1acc[2][4];                  // [mt][tt]
    #pragma unroll
    for (int mt = 0; mt < 2; ++mt)
        #pragma unroll
        for (int tt = 0; tt < 4; ++tt) {
            z1acc[mt][tt] = (f32x4){0,0,0,0};
            u1acc[mt][tt] = (f32x4){0,0,0,0};
        }
    #pragma unroll
    for (int kc = 0; kc < 2; ++kc) {
        const int g = kc * 4 + lg;
        bf16x8 ash[2], asl[2], adh[2], adl[2];
        #pragma unroll
        for (int mt = 0; mt < 2; ++mt) {
            const int off = g * PITCH + swz(g, mt * 16 + lc) * 8;
            ash[mt] = *reinterpret_cast<const bf16x8*>(&sH[off]);
            asl[mt] = *reinterpret_cast<const bf16x8*>(&sL[off]);
            adh[mt] = *reinterpret_cast<const bf16x8*>(&dH[off]);
            adl[mt] = *reinterpret_cast<const bf16x8*>(&dL[off]);
        }
        __builtin_amdgcn_s_setprio(1);
        #pragma unroll
        for (int tt = 0; tt < 4; ++tt) {
            #pragma unroll
            for (int mt = 0; mt < 2; ++mt) {
                z1acc[mt][tt] = __builtin_amdgcn_mfma_f32_16x16x32_bf16(ash[mt], B1h[kc][tt], z1acc[mt][tt], 0,0,0);
                z1acc[mt][tt] = __builtin_amdgcn_mfma_f32_16x16x32_bf16(asl[mt], B1h[kc][tt], z1acc[mt][tt], 0,0,0);
                z1acc[mt][tt] = __builtin_amdgcn_mfma_f32_16x16x32_bf16(ash[mt], B1l[kc][tt], z1acc[mt][tt], 0,0,0);
                u1acc[mt][tt] = __builtin_amdgcn_mfma_f32_16x16x32_bf16(adh[mt], B1h[kc][tt], u1acc[mt][tt], 0,0,0);
                u1acc[mt][tt] = __builtin_amdgcn_mfma_f32_16x16x32_bf16(adl[mt], B1h[kc][tt], u1acc[mt][tt], 0,0,0);
                u1acc[mt][tt] = __builtin_amdgcn_mfma_f32_16x16x32_bf16(adh[mt], B1l[kc][tt], u1acc[mt][tt], 0,0,0);
            }
        }
        __builtin_amdgcn_s_setprio(0);
    }

    // D layout: sample row = mt*16 + lg*4 + r, col h = hh[tt]
    // publish y1 = (z1+b1)^2 (split) + p-lo; p-hi after the alias barrier
    f32x4 p_[2][4];
    #pragma unroll
    for (int tt = 0; tt < 4; ++tt) {
        const int grp = hh[tt] >> 3;
        const int jb  = grp * PITCH + (hh[tt] & 7);
        #pragma unroll
        for (int mt = 0; mt < 2; ++mt) {
            #pragma unroll
            for (int r = 0; r < 4; ++r) {
                const float z = z1acc[mt][tt][r] + bb1[tt];
                const float pv = 2.f * z * u1acc[mt][tt][r];
                p_[mt][tt][r] = pv;
                const float y   = z * z;
                const ushort yh = f2bf(y);
                const int ii = swz(grp, mt * 16 + lg * 4 + r);
                yH[jb + ii * 8] = yh;
                yL[jb + ii * 8] = f2bf(y - bf2f(yh));
                pL[jb + ii * 8] = f2bf(pv - bf2f(f2bf(pv)));
            }
        }
    }
    __syncthreads();                                 // (2) all S-reads done

    #pragma unroll
    for (int tt = 0; tt < 4; ++tt) {
        const int grp = hh[tt] >> 3;
        const int jb  = grp * PITCH + (hh[tt] & 7);
        #pragma unroll
        for (int mt = 0; mt < 2; ++mt) {
            #pragma unroll
            for (int r = 0; r < 4; ++r) {
                const int ii = swz(grp, mt * 16 + lg * 4 + r);
                pH[jb + ii * 8] = f2bf(p_[mt][tt][r]);
            }
        }
    }
    __syncthreads();                                 // (3) pH visible

    // ---------- merged phase 2: z2 = y1@W2^T  AND  q = p@W2^T ----------
    f32x4 z2acc[2][4], qacc[2][4];
    #pragma unroll
    for (int mt = 0; mt < 2; ++mt)
        #pragma unroll
        for (int tt = 0; tt < 4; ++tt) {
            z2acc[mt][tt] = (f32x4){0,0,0,0};
            qacc[mt][tt]  = (f32x4){0,0,0,0};
        }
    #pragma unroll 2
    for (int kc = 0; kc < 8; ++kc) {
        const int g = kc * 4 + lg;
        bf16x8 bh[4], bl[4];
        #pragma unroll
        for (int tt = 0; tt < 4; ++tt) { bh[tt] = nbh[tt]; bl[tt] = nbl[tt]; }
        if (kc < 7) {                                // prefetch next-kc B2 frags
            const int gn = (kc + 1) * 4 + lg;
            #pragma unroll
            for (int tt = 0; tt < 4; ++tt) {
                const int o = (gn * 256 + hh[tt]) * 8;
                nbh[tt] = *reinterpret_cast<const bf16x8*>(ws + 32768 + o);
                nbl[tt] = *reinterpret_cast<const bf16x8*>(ws + 98304 + o);
            }
        }
        bf16x8 ayh[2], ayl[2], aph[2], apl[2];
        #pragma unroll
        for (int mt = 0; mt < 2; ++mt) {
            const int off = g * PITCH + swz(g, mt * 16 + lc) * 8;
            ayh[mt] = *reinterpret_cast<const bf16x8*>(&yH[off]);
            ayl[mt] = *reinterpret_cast<const bf16x8*>(&yL[off]);
            aph[mt] = *reinterpret_cast<const bf16x8*>(&pH[off]);
            apl[mt] = *reinterpret_cast<const bf16x8*>(&pL[off]);
        }
        __builtin_amdgcn_s_setprio(1);
        #pragma unroll
        for (int tt = 0; tt < 4; ++tt) {
            #pragma unroll
            for (int mt = 0; mt < 2; ++mt) {
                z2acc[mt][tt] = __builtin_amdgcn_mfma_f32_16x16x32_bf16(ayh[mt], bh[tt], z2acc[mt][tt], 0,0,0);
                z2acc[mt][tt] = __builtin_amdgcn_mfma_f32_16x16x32_bf16(ayl[mt], bh[tt], z2acc[mt][tt], 0,0,0);
                z2acc[mt][tt] = __builtin_amdgcn_mfma_f32_16x16x32_bf16(ayh[mt], bl[tt], z2acc[mt][tt], 0,0,0);
                qacc[mt][tt]  = __builtin_amdgcn_mfma_f32_16x16x32_bf16(aph[mt], bh[tt], qacc[mt][tt], 0,0,0);
                qacc[mt][tt]  = __builtin_amdgcn_mfma_f32_16x16x32_bf16(apl[mt], bh[tt], qacc[mt][tt], 0,0,0);
                qacc[mt][tt]  = __builtin_amdgcn_mfma_f32_16x16x32_bf16(aph[mt], bl[tt], qacc[mt][tt], 0,0,0);
            }
        }
        __builtin_amdgcn_s_setprio(0);
    }

    // ---------- epilogue: nn = sum w3*(z2+b2)^2 ; gd = sum 2*w3*(z2+b2)*q ----
    float nnp[2][4], gdp[2][4];
    #pragma unroll
    for (int mt = 0; mt < 2; ++mt)
        #pragma unroll
        for (int r = 0; r < 4; ++r) { nnp[mt][r] = 0.f; gdp[mt][r] = 0.f; }
    #pragma unroll
    for (int tt = 0; tt < 4; ++tt) {
        #pragma unroll
        for (int mt = 0; mt < 2; ++mt) {
            #pragma unroll
            for (int r = 0; r < 4; ++r) {
                const float z = z2acc[mt][tt][r] + bb2[tt];
                nnp[mt][r] += w3v[tt] * z * z;
                gdp[mt][r] += 2.f * w3v[tt] * z * qacc[mt][tt][r];
            }
        }
    }
    #pragma unroll
    for (int mt = 0; mt < 2; ++mt)
        #pragma unroll
        for (int r = 0; r < 4; ++r) {
            float a = nnp[mt][r], b = gdp[mt][r];
            #pragma unroll
            for (int o = 1; o < 16; o <<= 1) { a += __shfl_xor(a, o); b += __shfl_xor(b, o); }
            if (lc == 0) {
                red[0][wid][mt * 16 + lg * 4 + r] = a;
                red[1][wid][mt * 16 + lg * 4 + r] = b;
            }
        }
    __syncthreads();                                 // (4) red visible

    // ---------- finalize ----------
    if (t < SB) {
        const int i = t;
        float nn = 0.f, gd = 0.f;
        #pragma unroll
        for (int w = 0; w < 4; ++w) { nn += red[0][w][i]; gd += red[1][w][i]; }
        const float c  = csd[i][0];
        const float sd = csd[i][1];
        const int n = s0 + i;
        out[n]         = nn * c;                 // V
        out[N + n]     = 2.f * nn * sd + c * gd; // Vdot
        out[2 * N + n] = c;                      // circle
    }
}

extern "C" void kernel_launch(void* const* d_in, const int* in_sizes, int n_in,
                              void* d_out, int out_size, void* d_ws, size_t ws_size,
                              hipStream_t stream) {
    const float* S    = (const float*)d_in[0];
    const float* Sdot = (const float*)d_in[1];
    const float* W1   = (const float*)d_in[2];
    const float* b1   = (const float*)d_in[3];
    const float* W2   = (const float*)d_in[4];
    const float* b2   = (const float*)d_in[5];
    const float* W3   = (const float*)d_in[6];
    float* out = (float*)d_out;
    ushort* ws = (ushort*)d_ws;    // 320 KB weight planes

    prep_weights<<<40, 256, 0, stream>>>(W1, W2, ws);
    fused_mfma<<<N / SB, 256, 0, stream>>>(S, Sdot, b1, b2, W3, ws, out);
}